// Round 3
// baseline (7711.759 us; speedup 1.0000x reference)
//
#include <hip/hip_runtime.h>
#include <hip/hip_bf16.h>
#include <math.h>

// Problem constants
#define NB    1024      // batch rows == scan steps
#define SEQ   600
#define EDIM  300
#define HDIM  256
#define DIN   903       // 3*E + 3
#define GDIM  1024      // 4*H
#define SENT  0xFFFFFFFFu
#define L2E   1.4426950408889634f

// ---------------------------------------------------------------------------
// Kernel 1: conv — per row: 3 segment means of gathered embeddings + 3 cosines
// ---------------------------------------------------------------------------
__global__ __launch_bounds__(256) void conv_kernel(const int* __restrict__ x,
                                                   const float* __restrict__ emb,
                                                   float* __restrict__ X) {
    const int row = blockIdx.x;
    const int tid = threadIdx.x;
    const int* xr = x + (size_t)row * SEQ;

    __shared__ float seg[3][EDIM];
    __shared__ float scnt[3];
    __shared__ float reds[6];
    __shared__ float coss[3];

    if (tid < 6) reds[tid] = 0.f;
    if (tid < 3) scnt[tid] = 0.f;
    __syncthreads();

    {
        int c0 = 0, c1 = 0, c2 = 0;
        for (int t = tid; t < 200; t += 256) {
            c0 += (xr[t]       != 0);
            c1 += (xr[200 + t] != 0);
            c2 += (xr[400 + t] != 0);
        }
        float f0 = (float)c0, f1 = (float)c1, f2 = (float)c2;
        #pragma unroll
        for (int m = 1; m < 64; m <<= 1) {
            f0 += __shfl_xor(f0, m);
            f1 += __shfl_xor(f1, m);
            f2 += __shfl_xor(f2, m);
        }
        if ((tid & 63) == 0) {
            atomicAdd(&scnt[0], f0);
            atomicAdd(&scnt[1], f1);
            atomicAdd(&scnt[2], f2);
        }
    }
    __syncthreads();

    const float inv0 = 1.f / scnt[0], inv1 = 1.f / scnt[1], inv2 = 1.f / scnt[2];

    for (int d = tid; d < EDIM; d += 256) {
        float a0 = 0.f, a1 = 0.f, a2 = 0.f;
        for (int t = 0; t < 200; t++) {
            a0 += emb[(size_t)xr[t]       * EDIM + d];
            a1 += emb[(size_t)xr[200 + t] * EDIM + d];
            a2 += emb[(size_t)xr[400 + t] * EDIM + d];
        }
        seg[0][d] = a0 * inv0;
        seg[1][d] = a1 * inv1;
        seg[2][d] = a2 * inv2;
    }
    __syncthreads();

    {
        float p0 = 0, p1 = 0, p2 = 0, p3 = 0, p4 = 0, p5 = 0;
        for (int d = tid; d < EDIM; d += 256) {
            float a = seg[0][d], b = seg[1][d], c = seg[2][d];
            p0 += a * a; p1 += b * b; p2 += c * c;
            p3 += a * b; p4 += b * c; p5 += a * c;
        }
        #pragma unroll
        for (int m = 1; m < 64; m <<= 1) {
            p0 += __shfl_xor(p0, m); p1 += __shfl_xor(p1, m);
            p2 += __shfl_xor(p2, m); p3 += __shfl_xor(p3, m);
            p4 += __shfl_xor(p4, m); p5 += __shfl_xor(p5, m);
        }
        if ((tid & 63) == 0) {
            atomicAdd(&reds[0], p0); atomicAdd(&reds[1], p1);
            atomicAdd(&reds[2], p2); atomicAdd(&reds[3], p3);
            atomicAdd(&reds[4], p4); atomicAdd(&reds[5], p5);
        }
    }
    __syncthreads();
    if (tid == 0) {
        float nt = fmaxf(sqrtf(reds[0]), 1e-8f);
        float nu = fmaxf(sqrtf(reds[1]), 1e-8f);
        float nj = fmaxf(sqrtf(reds[2]), 1e-8f);
        coss[0] = reds[3] / (nt * nu);
        coss[1] = reds[4] / (nu * nj);
        coss[2] = reds[5] / (nt * nj);
    }
    __syncthreads();

    float* Xr = X + (size_t)row * DIN;
    for (int col = tid; col < DIN; col += 256) {
        float v;
        if      (col < 300)  v = seg[0][col];
        else if (col == 300) v = coss[0];
        else if (col < 601)  v = seg[1][col - 301];
        else if (col == 601) v = coss[1];
        else if (col < 902)  v = seg[2][col - 602];
        else                 v = coss[2];
        Xr[col] = v;
    }
}

// ---------------------------------------------------------------------------
// Kernel 2: GEMM  C[1024][1024] = A[1024][K] * B[1024][K]^T + bias1 + bias2
// ---------------------------------------------------------------------------
__global__ __launch_bounds__(256) void gemm_bias(const float* __restrict__ A,
                                                 const float* __restrict__ Bm,
                                                 const float* __restrict__ bias1,
                                                 const float* __restrict__ bias2,
                                                 float* __restrict__ C, int K) {
    __shared__ float As[16][68];
    __shared__ float Bs[16][68];
    const int tid = threadIdx.x;
    const int tx = tid & 15, ty = tid >> 4;
    const int m0 = blockIdx.y * 64, n0 = blockIdx.x * 64;

    float acc[4][4] = {};
    for (int k0 = 0; k0 < K; k0 += 16) {
        #pragma unroll
        for (int i = 0; i < 4; i++) {
            int e  = tid + i * 256;
            int rr = e >> 4, kk = e & 15;
            int k  = k0 + kk;
            As[kk][rr] = (k < K) ? A[(size_t)(m0 + rr) * K + k] : 0.f;
            Bs[kk][rr] = (k < K) ? Bm[(size_t)(n0 + rr) * K + k] : 0.f;
        }
        __syncthreads();
        #pragma unroll
        for (int kk = 0; kk < 16; kk++) {
            float a[4], b[4];
            #pragma unroll
            for (int i = 0; i < 4; i++) { a[i] = As[kk][ty * 4 + i]; b[i] = Bs[kk][tx * 4 + i]; }
            #pragma unroll
            for (int i = 0; i < 4; i++)
                #pragma unroll
                for (int j = 0; j < 4; j++)
                    acc[i][j] += a[i] * b[j];
        }
        __syncthreads();
    }
    #pragma unroll
    for (int i = 0; i < 4; i++) {
        int m = m0 + ty * 4 + i;
        #pragma unroll
        for (int j = 0; j < 4; j++) {
            int n = n0 + tx * 4 + j;
            C[(size_t)m * GDIM + n] = acc[i][j] + bias1[n] + bias2[n];
        }
    }
}

// ---------------------------------------------------------------------------
// Fast device math: sigmoid / tanh via native v_exp_f32 + v_rcp_f32.
// tanh(x) = 2*sigmoid(2x)-1; saturates correctly at |x| large (exp2->inf/0).
// ---------------------------------------------------------------------------
__device__ __forceinline__ float fsig(float x) {
    return __builtin_amdgcn_rcpf(1.f + __builtin_amdgcn_exp2f(-L2E * x));
}
__device__ __forceinline__ float ftanh(float x) {
    return 2.f * __builtin_amdgcn_rcpf(1.f + __builtin_amdgcn_exp2f(-2.f * L2E * x)) - 1.f;
}

__device__ __forceinline__ unsigned ald(const unsigned* p) {
    return __hip_atomic_load(p, __ATOMIC_RELAXED, __HIP_MEMORY_SCOPE_AGENT);
}

// poll one float4 (4 write-once dwords) until none is the sentinel
__device__ __forceinline__ float4 poll4(const unsigned* p) {
    unsigned a = SENT, b = SENT, c = SENT, d = SENT;
    int gd = 0;
    do {
        if (a == SENT) a = ald(p + 0);
        if (b == SENT) b = ald(p + 1);
        if (c == SENT) c = ald(p + 2);
        if (d == SENT) d = ald(p + 3);
    } while (((a == SENT) | (b == SENT) | (c == SENT) | (d == SENT)) && ++gd < (1 << 20));
    return make_float4(__uint_as_float(a), __uint_as_float(b),
                       __uint_as_float(c), __uint_as_float(d));
}

// poll two float4 rows concurrently (overlapped round trips)
__device__ __forceinline__ void poll8(const unsigned* p1, const unsigned* p2,
                                      float4& o1, float4& o2) {
    unsigned a = SENT, b = SENT, c = SENT, d = SENT;
    unsigned e = SENT, f = SENT, g = SENT, h = SENT;
    int gd = 0;
    do {
        if (a == SENT) a = ald(p1 + 0);
        if (b == SENT) b = ald(p1 + 1);
        if (c == SENT) c = ald(p1 + 2);
        if (d == SENT) d = ald(p1 + 3);
        if (e == SENT) e = ald(p2 + 0);
        if (f == SENT) f = ald(p2 + 1);
        if (g == SENT) g = ald(p2 + 2);
        if (h == SENT) h = ald(p2 + 3);
    } while (((a == SENT) | (b == SENT) | (c == SENT) | (d == SENT) |
              (e == SENT) | (f == SENT) | (g == SENT) | (h == SENT)) && ++gd < (1 << 20));
    o1 = make_float4(__uint_as_float(a), __uint_as_float(b),
                     __uint_as_float(c), __uint_as_float(d));
    o2 = make_float4(__uint_as_float(e), __uint_as_float(f),
                     __uint_as_float(g), __uint_as_float(h));
}

// ---------------------------------------------------------------------------
// Kernel 3: fused 2-layer LSTM, BARRIER-FREE dataflow.
// 16 WGs x 1024 threads. WGs 0..7 = layer 1, 8..15 = layer 2; WG owns h-slice
// [w*32, w*32+32). Wave = 2 elements x (4 gates x 8 k-chunks):
//   lane: half=lane>>5 (element), gate=(lane>>3)&3, q=lane&7.
// Per step, each wave independently: polls full h(t-1) row (write-once
// sentinel dwords, agent scope), stages to a wave-PRIVATE LDS buffer (no
// cross-wave races -> no barrier), matvec from register weights, 3-shuffle
// q-reduce, parallel per-gate nonlinearity (native exp2), 3-shuffle collect,
// register c update, 2 dword h stores. L2 additionally polls x=ys1[t] and
// applies Wih1 from registers. LDS reads are q-rotated -> bank-conflict-free;
// weights pre-rotated at load so register arrays keep constant indices.
// ---------------------------------------------------------------------------
__global__ __launch_bounds__(1024, 4) void lstm_fused(
    const float* __restrict__ G1,
    const float* __restrict__ Whh0,
    const float* __restrict__ Wih1,
    const float* __restrict__ Whh1,
    const float* __restrict__ b_ih1,
    const float* __restrict__ b_hh1,
    const float* __restrict__ h0,
    const float* __restrict__ c0,
    float* ys1, float* ys2, float* out)
{
    const int  blk   = blockIdx.x;
    const bool isL2  = blk >= 8;
    const int  w     = blk & 7;
    const int  tid   = threadIdx.x;
    const int  wv    = tid >> 6;
    const int  lane  = tid & 63;
    const int  half  = lane >> 5;
    const int  gate  = (lane >> 3) & 3;
    const int  q     = lane & 7;
    const int  eloc  = wv * 2 + half;        // 0..31
    const int  gelem = w * 32 + eloc;        // 0..255
    const int  grow  = gate * 256 + gelem;   // 0..1023
    const int  layer = isL2 ? 1 : 0;
    const bool isElemLane = ((lane & 31) == 0);

    __shared__ __align__(16) float hbuf[16][256];
    __shared__ __align__(16) float xbuf[16][256];

    // register-resident weights, pre-rotated by q for conflict-free LDS reads
    float4 wh[8], wi[8];
    {
        const float4* p = (const float4*)((isL2 ? Whh1 : Whh0) + (size_t)grow * HDIM) + q * 8;
        #pragma unroll
        for (int j = 0; j < 8; j++) wh[j] = p[(j + q) & 7];
    }
    float bsum = 0.f;
    if (isL2) {
        const float4* p = (const float4*)(Wih1 + (size_t)grow * HDIM) + q * 8;
        #pragma unroll
        for (int j = 0; j < 8; j++) wi[j] = p[(j + q) & 7];
        bsum = b_ih1[grow] + b_hh1[grow];
    }

    float cst = c0[layer * HDIM + gelem];    // live in elem lanes (0,32)

    float* ysL = isL2 ? ys2 : ys1;
    float* hb = &hbuf[wv][0];
    float* xb = &xbuf[wv][0];

    for (int t = 0; t < NB; t++) {
        // x-gate contribution: L1 from precomputed GEMM, L2 bias (prefetch early)
        float gval = isL2 ? bsum : G1[(size_t)t * GDIM + grow];

        // ---- acquire inputs ----
        float4 hvec, xvec;
        if (!isL2) {
            if (t == 0) hvec = *(const float4*)&h0[4 * lane];
            else        hvec = poll4((const unsigned*)&ys1[(size_t)(t - 1) * HDIM + 4 * lane]);
        } else {
            if (t == 0) {
                hvec = *(const float4*)&h0[HDIM + 4 * lane];
                xvec = poll4((const unsigned*)&ys1[4 * lane]);
            } else {
                poll8((const unsigned*)&ys2[(size_t)(t - 1) * HDIM + 4 * lane],
                      (const unsigned*)&ys1[(size_t)t * HDIM + 4 * lane],
                      hvec, xvec);
            }
        }

        // stage to wave-private LDS (ordering via lgkmcnt only, no barrier)
        ((float4*)hb)[lane] = hvec;
        if (isL2) ((float4*)xb)[lane] = xvec;

        // ---- matvec: 32-wide chunk of this lane's gate row ----
        float acc = 0.f;
        {
            const float4* hrow = (const float4*)&hb[q * 32];
            #pragma unroll
            for (int j = 0; j < 8; j++) {
                float4 h4 = hrow[(j + q) & 7];
                acc += h4.x * wh[j].x + h4.y * wh[j].y + h4.z * wh[j].z + h4.w * wh[j].w;
            }
            if (isL2) {
                const float4* xrow = (const float4*)&xb[q * 32];
                #pragma unroll
                for (int j = 0; j < 8; j++) {
                    float4 x4 = xrow[(j + q) & 7];
                    acc += x4.x * wi[j].x + x4.y * wi[j].y + x4.z * wi[j].z + x4.w * wi[j].w;
                }
            }
        }
        // reduce over q (8 lanes)
        acc += __shfl_xor(acc, 1);
        acc += __shfl_xor(acc, 2);
        acc += __shfl_xor(acc, 4);
        float tot = acc + gval;                      // valid at q==0 lanes

        // per-gate nonlinearity in parallel (i,f,o: sigmoid; g: tanh)
        float nl = (gate == 2) ? ftanh(tot) : fsig(tot);

        // collect i,f,g,o to elem lanes (0 and 32)
        const int base = lane & 32;
        float fv = __shfl(nl, base | 8, 64);
        float gv = __shfl(nl, base | 16, 64);
        float ov = __shfl(nl, base | 24, 64);

        float cnew = fv * cst + nl * gv;             // nl==i at elem lanes
        float hnew = ov * ftanh(cnew);
        if (isElemLane) {
            cst = cnew;
            __hip_atomic_store((unsigned*)&ysL[(size_t)t * HDIM + gelem],
                               __float_as_uint(hnew),
                               __ATOMIC_RELAXED, __HIP_MEMORY_SCOPE_AGENT);
            if (t == NB - 1) {
                out[1024 + layer * HDIM + gelem] = hnew;   // hn
                out[1536 + layer * HDIM + gelem] = cnew;   // cn
            }
        }
    }
}

// ---------------------------------------------------------------------------
// Kernel 4: fc head
// ---------------------------------------------------------------------------
__global__ __launch_bounds__(256) void fc_kernel(const float* __restrict__ ys2,
                                                 const float* __restrict__ fc_w,
                                                 const float* __restrict__ fc_b,
                                                 float* __restrict__ out) {
    const int row  = blockIdx.x * 4 + (threadIdx.x >> 6);
    const int lane = threadIdx.x & 63;
    float4 y = ((const float4*)(ys2 + (size_t)row * HDIM))[lane];
    float4 wv = ((const float4*)fc_w)[lane];
    float d = y.x * wv.x + y.y * wv.y + y.z * wv.z + y.w * wv.w;
    #pragma unroll
    for (int m = 1; m < 64; m <<= 1) d += __shfl_xor(d, m);
    if (lane == 0) out[row] = 1.f / (1.f + expf(-(d + fc_b[0])));
}

// ---------------------------------------------------------------------------
extern "C" void kernel_launch(void* const* d_in, const int* in_sizes, int n_in,
                              void* d_out, int out_size, void* d_ws, size_t ws_size,
                              hipStream_t stream) {
    const int*   x     = (const int*)  d_in[0];
    const float* h0    = (const float*)d_in[1];
    const float* c0    = (const float*)d_in[2];
    const float* emb   = (const float*)d_in[3];
    const float* w_ih0 = (const float*)d_in[4];
    const float* w_hh0 = (const float*)d_in[5];
    const float* b_ih0 = (const float*)d_in[6];
    const float* b_hh0 = (const float*)d_in[7];
    const float* w_ih1 = (const float*)d_in[8];
    const float* w_hh1 = (const float*)d_in[9];
    const float* b_ih1 = (const float*)d_in[10];
    const float* b_hh1 = (const float*)d_in[11];
    const float* fc_w  = (const float*)d_in[12];
    const float* fc_b  = (const float*)d_in[13];
    float* out = (float*)d_out;

    // workspace layout (floats)
    float* X   = (float*)d_ws;                  // 1024*903
    float* G1  = X + (size_t)NB * DIN;          // 1024*1024
    float* ys1 = G1 + (size_t)NB * GDIM;        // 1024*256
    float* ys2 = ys1 + (size_t)NB * HDIM;       // 1024*256

    // sentinel-fill both exchange buffers (0xFFFFFFFF = NaN, never produced)
    hipMemsetAsync(ys1, 0xFF, 2 * (size_t)NB * HDIM * sizeof(float), stream);

    conv_kernel<<<NB, 256, 0, stream>>>(x, emb, X);

    gemm_bias<<<dim3(16, 16), 256, 0, stream>>>(X, w_ih0, b_ih0, b_hh0, G1, DIN);

    lstm_fused<<<16, 1024, 0, stream>>>(G1, w_hh0, w_ih1, w_hh1, b_ih1, b_hh1,
                                        h0, c0, ys1, ys2, out);

    fc_kernel<<<NB / 4, 256, 0, stream>>>(ys2, fc_w, fc_b, out);
}

// Round 4
// 4064.263 us; speedup vs baseline: 1.8975x; 1.8975x over previous
//
#include <hip/hip_runtime.h>
#include <hip/hip_bf16.h>
#include <math.h>

// Problem constants
#define NB    1024      // batch rows == scan steps
#define SEQ   600
#define EDIM  300
#define HDIM  256
#define DIN   903       // 3*E + 3
#define GDIM  1024      // 4*H
#define SENT  0xFFFFFFFFu
#define L2E   1.4426950408889634f

// ---------------------------------------------------------------------------
// Kernel 1: conv — per row: 3 segment means of gathered embeddings + 3 cosines
// ---------------------------------------------------------------------------
__global__ __launch_bounds__(256) void conv_kernel(const int* __restrict__ x,
                                                   const float* __restrict__ emb,
                                                   float* __restrict__ X) {
    const int row = blockIdx.x;
    const int tid = threadIdx.x;
    const int* xr = x + (size_t)row * SEQ;

    __shared__ float seg[3][EDIM];
    __shared__ float scnt[3];
    __shared__ float reds[6];
    __shared__ float coss[3];

    if (tid < 6) reds[tid] = 0.f;
    if (tid < 3) scnt[tid] = 0.f;
    __syncthreads();

    {
        int c0 = 0, c1 = 0, c2 = 0;
        for (int t = tid; t < 200; t += 256) {
            c0 += (xr[t]       != 0);
            c1 += (xr[200 + t] != 0);
            c2 += (xr[400 + t] != 0);
        }
        float f0 = (float)c0, f1 = (float)c1, f2 = (float)c2;
        #pragma unroll
        for (int m = 1; m < 64; m <<= 1) {
            f0 += __shfl_xor(f0, m);
            f1 += __shfl_xor(f1, m);
            f2 += __shfl_xor(f2, m);
        }
        if ((tid & 63) == 0) {
            atomicAdd(&scnt[0], f0);
            atomicAdd(&scnt[1], f1);
            atomicAdd(&scnt[2], f2);
        }
    }
    __syncthreads();

    const float inv0 = 1.f / scnt[0], inv1 = 1.f / scnt[1], inv2 = 1.f / scnt[2];

    for (int d = tid; d < EDIM; d += 256) {
        float a0 = 0.f, a1 = 0.f, a2 = 0.f;
        for (int t = 0; t < 200; t++) {
            a0 += emb[(size_t)xr[t]       * EDIM + d];
            a1 += emb[(size_t)xr[200 + t] * EDIM + d];
            a2 += emb[(size_t)xr[400 + t] * EDIM + d];
        }
        seg[0][d] = a0 * inv0;
        seg[1][d] = a1 * inv1;
        seg[2][d] = a2 * inv2;
    }
    __syncthreads();

    {
        float p0 = 0, p1 = 0, p2 = 0, p3 = 0, p4 = 0, p5 = 0;
        for (int d = tid; d < EDIM; d += 256) {
            float a = seg[0][d], b = seg[1][d], c = seg[2][d];
            p0 += a * a; p1 += b * b; p2 += c * c;
            p3 += a * b; p4 += b * c; p5 += a * c;
        }
        #pragma unroll
        for (int m = 1; m < 64; m <<= 1) {
            p0 += __shfl_xor(p0, m); p1 += __shfl_xor(p1, m);
            p2 += __shfl_xor(p2, m); p3 += __shfl_xor(p3, m);
            p4 += __shfl_xor(p4, m); p5 += __shfl_xor(p5, m);
        }
        if ((tid & 63) == 0) {
            atomicAdd(&reds[0], p0); atomicAdd(&reds[1], p1);
            atomicAdd(&reds[2], p2); atomicAdd(&reds[3], p3);
            atomicAdd(&reds[4], p4); atomicAdd(&reds[5], p5);
        }
    }
    __syncthreads();
    if (tid == 0) {
        float nt = fmaxf(sqrtf(reds[0]), 1e-8f);
        float nu = fmaxf(sqrtf(reds[1]), 1e-8f);
        float nj = fmaxf(sqrtf(reds[2]), 1e-8f);
        coss[0] = reds[3] / (nt * nu);
        coss[1] = reds[4] / (nu * nj);
        coss[2] = reds[5] / (nt * nj);
    }
    __syncthreads();

    float* Xr = X + (size_t)row * DIN;
    for (int col = tid; col < DIN; col += 256) {
        float v;
        if      (col < 300)  v = seg[0][col];
        else if (col == 300) v = coss[0];
        else if (col < 601)  v = seg[1][col - 301];
        else if (col == 601) v = coss[1];
        else if (col < 902)  v = seg[2][col - 602];
        else                 v = coss[2];
        Xr[col] = v;
    }
}

// ---------------------------------------------------------------------------
// Kernel 2: GEMM  C[1024][1024] = A[1024][K] * B[1024][K]^T + bias1 + bias2
// ---------------------------------------------------------------------------
__global__ __launch_bounds__(256) void gemm_bias(const float* __restrict__ A,
                                                 const float* __restrict__ Bm,
                                                 const float* __restrict__ bias1,
                                                 const float* __restrict__ bias2,
                                                 float* __restrict__ C, int K) {
    __shared__ float As[16][68];
    __shared__ float Bs[16][68];
    const int tid = threadIdx.x;
    const int tx = tid & 15, ty = tid >> 4;
    const int m0 = blockIdx.y * 64, n0 = blockIdx.x * 64;

    float acc[4][4] = {};
    for (int k0 = 0; k0 < K; k0 += 16) {
        #pragma unroll
        for (int i = 0; i < 4; i++) {
            int e  = tid + i * 256;
            int rr = e >> 4, kk = e & 15;
            int k  = k0 + kk;
            As[kk][rr] = (k < K) ? A[(size_t)(m0 + rr) * K + k] : 0.f;
            Bs[kk][rr] = (k < K) ? Bm[(size_t)(n0 + rr) * K + k] : 0.f;
        }
        __syncthreads();
        #pragma unroll
        for (int kk = 0; kk < 16; kk++) {
            float a[4], b[4];
            #pragma unroll
            for (int i = 0; i < 4; i++) { a[i] = As[kk][ty * 4 + i]; b[i] = Bs[kk][tx * 4 + i]; }
            #pragma unroll
            for (int i = 0; i < 4; i++)
                #pragma unroll
                for (int j = 0; j < 4; j++)
                    acc[i][j] += a[i] * b[j];
        }
        __syncthreads();
    }
    #pragma unroll
    for (int i = 0; i < 4; i++) {
        int m = m0 + ty * 4 + i;
        #pragma unroll
        for (int j = 0; j < 4; j++) {
            int n = n0 + tx * 4 + j;
            C[(size_t)m * GDIM + n] = acc[i][j] + bias1[n] + bias2[n];
        }
    }
}

// ---------------------------------------------------------------------------
// Fast device math: sigmoid / tanh via native v_exp_f32 + v_rcp_f32.
// ---------------------------------------------------------------------------
__device__ __forceinline__ float fsig(float x) {
    return __builtin_amdgcn_rcpf(1.f + __builtin_amdgcn_exp2f(-L2E * x));
}
__device__ __forceinline__ float ftanh(float x) {
    return 2.f * __builtin_amdgcn_rcpf(1.f + __builtin_amdgcn_exp2f(-2.f * L2E * x)) - 1.f;
}

__device__ __forceinline__ unsigned ald(const unsigned* p) {
    return __hip_atomic_load(p, __ATOMIC_RELAXED, __HIP_MEMORY_SCOPE_AGENT);
}

// poll one float4 (4 write-once dwords) until none is the sentinel
__device__ __forceinline__ float4 poll4(const unsigned* p) {
    unsigned a = SENT, b = SENT, c = SENT, d = SENT;
    int gd = 0;
    do {
        if (a == SENT) a = ald(p + 0);
        if (b == SENT) b = ald(p + 1);
        if (c == SENT) c = ald(p + 2);
        if (d == SENT) d = ald(p + 3);
    } while (((a == SENT) | (b == SENT) | (c == SENT) | (d == SENT)) && ++gd < (1 << 22));
    return make_float4(__uint_as_float(a), __uint_as_float(b),
                       __uint_as_float(c), __uint_as_float(d));
}

// ---------------------------------------------------------------------------
// Kernel 3: fused 2-layer LSTM. 16 WGs x 1024 threads; WGs 0..7 = layer 1,
// 8..15 = layer 2; WG owns h-slice [w*32, w*32+32).
// Exchange: write-once sentinel rows ys[t][256] (agent-scope atomics).
// ONE poller wave per WG (wave 0) polls the full 256-dword h row and stages
// it into double-buffered LDS; L2 WGs additionally use wave 1 to poll the
// x-input row ys1[t]. Publication to the other 15 waves via LDS flag
// (workgroup-scope release/acquire, s_sleep spin) — NO __syncthreads, so
// producers' outstanding global store-acks never enter the local chain.
// Compute mapping (per wave): lane = half(1)|gate(2)|q(3); wave computes 2 h
// elements; per-gate nonlinearity runs in parallel lanes with native exp2.
// amdgpu_waves_per_eu(4,4): occupancy beyond 1 block/CU is useless (grid=16
// on 256 CUs) -> regalloc may use ~512 VGPRs -> weight arrays stay resident.
// ---------------------------------------------------------------------------
__global__ __attribute__((amdgpu_flat_work_group_size(1024, 1024),
                          amdgpu_waves_per_eu(4, 4)))
void lstm_fused(
    const float* __restrict__ G1,
    const float* __restrict__ Whh0,
    const float* __restrict__ Wih1,
    const float* __restrict__ Whh1,
    const float* __restrict__ b_ih1,
    const float* __restrict__ b_hh1,
    const float* __restrict__ h0,
    const float* __restrict__ c0,
    float* ys1, float* ys2, float* out)
{
    const int  blk   = blockIdx.x;
    const bool isL2  = blk >= 8;
    const int  w     = blk & 7;
    const int  tid   = threadIdx.x;
    const int  wv    = tid >> 6;
    const int  lane  = tid & 63;
    const int  half  = lane >> 5;
    const int  gate  = (lane >> 3) & 3;
    const int  q     = lane & 7;
    const int  eloc  = wv * 2 + half;        // 0..31
    const int  gelem = w * 32 + eloc;        // 0..255
    const int  grow  = gate * 256 + gelem;   // 0..1023
    const int  layer = isL2 ? 1 : 0;
    const bool isElemLane = ((lane & 31) == 0);

    __shared__ __align__(16) float hbuf[2][256];
    __shared__ __align__(16) float xbuf[2][256];
    __shared__ int hflag;
    __shared__ int xflag;

    if (tid == 0) { hflag = 0; xflag = 0; }

    // register-resident weights, pre-rotated by q for conflict-free LDS reads
    float4 wh[8], wi[8];
    {
        const float4* p = (const float4*)((isL2 ? Whh1 : Whh0) + (size_t)grow * HDIM) + q * 8;
        #pragma unroll
        for (int j = 0; j < 8; j++) wh[j] = p[(j + q) & 7];
    }
    float bsum = 0.f;
    if (isL2) {
        const float4* p = (const float4*)(Wih1 + (size_t)grow * HDIM) + q * 8;
        #pragma unroll
        for (int j = 0; j < 8; j++) wi[j] = p[(j + q) & 7];
        bsum = b_ih1[grow] + b_hh1[grow];
    } else {
        #pragma unroll
        for (int j = 0; j < 8; j++) wi[j] = make_float4(0.f, 0.f, 0.f, 0.f);
    }

    float cst = c0[layer * HDIM + gelem];    // live in elem lanes (0,32)

    float* ysL = isL2 ? ys2 : ys1;

    __syncthreads();   // flags initialized (only barrier in the kernel)

    for (int t = 0; t < NB; t++) {
        const int b = t & 1;
        // x-gate contribution: L1 from precomputed GEMM, L2 bias
        float gval = isL2 ? bsum : G1[(size_t)t * GDIM + grow];

        // ---- poller wave(s): stage inputs into LDS, publish via flag ----
        if (wv == 0) {
            float4 hv;
            if (t == 0) hv = *(const float4*)&h0[layer * HDIM + 4 * lane];
            else        hv = poll4((const unsigned*)&ysL[(size_t)(t - 1) * HDIM + 4 * lane]);
            ((float4*)&hbuf[b][0])[lane] = hv;
            __hip_atomic_store(&hflag, t + 1, __ATOMIC_RELEASE,
                               __HIP_MEMORY_SCOPE_WORKGROUP);
        } else if (isL2 && wv == 1) {
            float4 xv = poll4((const unsigned*)&ys1[(size_t)t * HDIM + 4 * lane]);
            ((float4*)&xbuf[b][0])[lane] = xv;
            __hip_atomic_store(&xflag, t + 1, __ATOMIC_RELEASE,
                               __HIP_MEMORY_SCOPE_WORKGROUP);
        }

        // ---- all waves: wait for staged inputs (LDS spin, no barrier) ----
        {
            int gd = 0;
            while (__hip_atomic_load(&hflag, __ATOMIC_ACQUIRE,
                                     __HIP_MEMORY_SCOPE_WORKGROUP) < t + 1) {
                __builtin_amdgcn_s_sleep(1);
                if (++gd > (1 << 22)) break;
            }
            if (isL2) {
                gd = 0;
                while (__hip_atomic_load(&xflag, __ATOMIC_ACQUIRE,
                                         __HIP_MEMORY_SCOPE_WORKGROUP) < t + 1) {
                    __builtin_amdgcn_s_sleep(1);
                    if (++gd > (1 << 22)) break;
                }
            }
        }

        // ---- matvec: 32-wide chunk of this lane's gate row ----
        float acc = 0.f;
        {
            const float4* hrow = (const float4*)&hbuf[b][q * 32];
            #pragma unroll
            for (int j = 0; j < 8; j++) {
                float4 h4 = hrow[(j + q) & 7];
                acc += h4.x * wh[j].x + h4.y * wh[j].y + h4.z * wh[j].z + h4.w * wh[j].w;
            }
            if (isL2) {
                const float4* xrow = (const float4*)&xbuf[b][q * 32];
                #pragma unroll
                for (int j = 0; j < 8; j++) {
                    float4 x4 = xrow[(j + q) & 7];
                    acc += x4.x * wi[j].x + x4.y * wi[j].y + x4.z * wi[j].z + x4.w * wi[j].w;
                }
            }
        }
        // reduce over q (8 lanes)
        acc += __shfl_xor(acc, 1);
        acc += __shfl_xor(acc, 2);
        acc += __shfl_xor(acc, 4);
        float tot = acc + gval;

        // per-gate nonlinearity in parallel (i,f,o: sigmoid; g: tanh)
        float nl = (gate == 2) ? ftanh(tot) : fsig(tot);

        // collect i,f,g,o to elem lanes (0 and 32)
        const int base = lane & 32;
        float fv = __shfl(nl, base | 8, 64);
        float gv = __shfl(nl, base | 16, 64);
        float ov = __shfl(nl, base | 24, 64);

        float cnew = fv * cst + nl * gv;             // nl==i at elem lanes
        float hnew = ov * ftanh(cnew);
        if (isElemLane) {
            cst = cnew;
            __hip_atomic_store((unsigned*)&ysL[(size_t)t * HDIM + gelem],
                               __float_as_uint(hnew),
                               __ATOMIC_RELAXED, __HIP_MEMORY_SCOPE_AGENT);
            if (t == NB - 1) {
                out[1024 + layer * HDIM + gelem] = hnew;   // hn
                out[1536 + layer * HDIM + gelem] = cnew;   // cn
            }
        }
    }
}

// ---------------------------------------------------------------------------
// Kernel 4: fc head
// ---------------------------------------------------------------------------
__global__ __launch_bounds__(256) void fc_kernel(const float* __restrict__ ys2,
                                                 const float* __restrict__ fc_w,
                                                 const float* __restrict__ fc_b,
                                                 float* __restrict__ out) {
    const int row  = blockIdx.x * 4 + (threadIdx.x >> 6);
    const int lane = threadIdx.x & 63;
    float4 y = ((const float4*)(ys2 + (size_t)row * HDIM))[lane];
    float4 wv = ((const float4*)fc_w)[lane];
    float d = y.x * wv.x + y.y * wv.y + y.z * wv.z + y.w * wv.w;
    #pragma unroll
    for (int m = 1; m < 64; m <<= 1) d += __shfl_xor(d, m);
    if (lane == 0) out[row] = 1.f / (1.f + expf(-(d + fc_b[0])));
}

// ---------------------------------------------------------------------------
extern "C" void kernel_launch(void* const* d_in, const int* in_sizes, int n_in,
                              void* d_out, int out_size, void* d_ws, size_t ws_size,
                              hipStream_t stream) {
    const int*   x     = (const int*)  d_in[0];
    const float* h0    = (const float*)d_in[1];
    const float* c0    = (const float*)d_in[2];
    const float* emb   = (const float*)d_in[3];
    const float* w_ih0 = (const float*)d_in[4];
    const float* w_hh0 = (const float*)d_in[5];
    const float* b_ih0 = (const float*)d_in[6];
    const float* b_hh0 = (const float*)d_in[7];
    const float* w_ih1 = (const float*)d_in[8];
    const float* w_hh1 = (const float*)d_in[9];
    const float* b_ih1 = (const float*)d_in[10];
    const float* b_hh1 = (const float*)d_in[11];
    const float* fc_w  = (const float*)d_in[12];
    const float* fc_b  = (const float*)d_in[13];
    float* out = (float*)d_out;

    // workspace layout (floats)
    float* X   = (float*)d_ws;                  // 1024*903
    float* G1  = X + (size_t)NB * DIN;          // 1024*1024
    float* ys1 = G1 + (size_t)NB * GDIM;        // 1024*256
    float* ys2 = ys1 + (size_t)NB * HDIM;       // 1024*256

    // sentinel-fill both exchange buffers (0xFFFFFFFF = NaN, never produced)
    hipMemsetAsync(ys1, 0xFF, 2 * (size_t)NB * HDIM * sizeof(float), stream);

    conv_kernel<<<NB, 256, 0, stream>>>(x, emb, X);

    gemm_bias<<<dim3(16, 16), 256, 0, stream>>>(X, w_ih0, b_ih0, b_hh0, G1, DIN);

    lstm_fused<<<16, 1024, 0, stream>>>(G1, w_hh0, w_ih1, w_hh1, b_ih1, b_hh1,
                                        h0, c0, ys1, ys2, out);

    fc_kernel<<<NB / 4, 256, 0, stream>>>(ys2, fc_w, fc_b, out);
}

// Round 5
// 3839.020 us; speedup vs baseline: 2.0088x; 1.0587x over previous
//
#include <hip/hip_runtime.h>
#include <hip/hip_bf16.h>
#include <math.h>

// Problem constants
#define NB    1024      // batch rows == scan steps
#define SEQ   600
#define EDIM  300
#define HDIM  256
#define DIN   903       // 3*E + 3
#define GDIM  1024      // 4*H
#define SENT  0xFFFFFFFFu
#define L2E   1.4426950408889634f

// ---------------------------------------------------------------------------
// Kernel 1: conv — per row: 3 segment means of gathered embeddings + 3 cosines
// ---------------------------------------------------------------------------
__global__ __launch_bounds__(256) void conv_kernel(const int* __restrict__ x,
                                                   const float* __restrict__ emb,
                                                   float* __restrict__ X) {
    const int row = blockIdx.x;
    const int tid = threadIdx.x;
    const int* xr = x + (size_t)row * SEQ;

    __shared__ float seg[3][EDIM];
    __shared__ float scnt[3];
    __shared__ float reds[6];
    __shared__ float coss[3];

    if (tid < 6) reds[tid] = 0.f;
    if (tid < 3) scnt[tid] = 0.f;
    __syncthreads();

    {
        int c0 = 0, c1 = 0, c2 = 0;
        for (int t = tid; t < 200; t += 256) {
            c0 += (xr[t]       != 0);
            c1 += (xr[200 + t] != 0);
            c2 += (xr[400 + t] != 0);
        }
        float f0 = (float)c0, f1 = (float)c1, f2 = (float)c2;
        #pragma unroll
        for (int m = 1; m < 64; m <<= 1) {
            f0 += __shfl_xor(f0, m);
            f1 += __shfl_xor(f1, m);
            f2 += __shfl_xor(f2, m);
        }
        if ((tid & 63) == 0) {
            atomicAdd(&scnt[0], f0);
            atomicAdd(&scnt[1], f1);
            atomicAdd(&scnt[2], f2);
        }
    }
    __syncthreads();

    const float inv0 = 1.f / scnt[0], inv1 = 1.f / scnt[1], inv2 = 1.f / scnt[2];

    for (int d = tid; d < EDIM; d += 256) {
        float a0 = 0.f, a1 = 0.f, a2 = 0.f;
        for (int t = 0; t < 200; t++) {
            a0 += emb[(size_t)xr[t]       * EDIM + d];
            a1 += emb[(size_t)xr[200 + t] * EDIM + d];
            a2 += emb[(size_t)xr[400 + t] * EDIM + d];
        }
        seg[0][d] = a0 * inv0;
        seg[1][d] = a1 * inv1;
        seg[2][d] = a2 * inv2;
    }
    __syncthreads();

    {
        float p0 = 0, p1 = 0, p2 = 0, p3 = 0, p4 = 0, p5 = 0;
        for (int d = tid; d < EDIM; d += 256) {
            float a = seg[0][d], b = seg[1][d], c = seg[2][d];
            p0 += a * a; p1 += b * b; p2 += c * c;
            p3 += a * b; p4 += b * c; p5 += a * c;
        }
        #pragma unroll
        for (int m = 1; m < 64; m <<= 1) {
            p0 += __shfl_xor(p0, m); p1 += __shfl_xor(p1, m);
            p2 += __shfl_xor(p2, m); p3 += __shfl_xor(p3, m);
            p4 += __shfl_xor(p4, m); p5 += __shfl_xor(p5, m);
        }
        if ((tid & 63) == 0) {
            atomicAdd(&reds[0], p0); atomicAdd(&reds[1], p1);
            atomicAdd(&reds[2], p2); atomicAdd(&reds[3], p3);
            atomicAdd(&reds[4], p4); atomicAdd(&reds[5], p5);
        }
    }
    __syncthreads();
    if (tid == 0) {
        float nt = fmaxf(sqrtf(reds[0]), 1e-8f);
        float nu = fmaxf(sqrtf(reds[1]), 1e-8f);
        float nj = fmaxf(sqrtf(reds[2]), 1e-8f);
        coss[0] = reds[3] / (nt * nu);
        coss[1] = reds[4] / (nu * nj);
        coss[2] = reds[5] / (nt * nj);
    }
    __syncthreads();

    float* Xr = X + (size_t)row * DIN;
    for (int col = tid; col < DIN; col += 256) {
        float v;
        if      (col < 300)  v = seg[0][col];
        else if (col == 300) v = coss[0];
        else if (col < 601)  v = seg[1][col - 301];
        else if (col == 601) v = coss[1];
        else if (col < 902)  v = seg[2][col - 602];
        else                 v = coss[2];
        Xr[col] = v;
    }
}

// ---------------------------------------------------------------------------
// Kernel 2: GEMM  C[1024][1024] = A[1024][K] * B[1024][K]^T + bias1 + bias2
// ---------------------------------------------------------------------------
__global__ __launch_bounds__(256) void gemm_bias(const float* __restrict__ A,
                                                 const float* __restrict__ Bm,
                                                 const float* __restrict__ bias1,
                                                 const float* __restrict__ bias2,
                                                 float* __restrict__ C, int K) {
    __shared__ float As[16][68];
    __shared__ float Bs[16][68];
    const int tid = threadIdx.x;
    const int tx = tid & 15, ty = tid >> 4;
    const int m0 = blockIdx.y * 64, n0 = blockIdx.x * 64;

    float acc[4][4] = {};
    for (int k0 = 0; k0 < K; k0 += 16) {
        #pragma unroll
        for (int i = 0; i < 4; i++) {
            int e  = tid + i * 256;
            int rr = e >> 4, kk = e & 15;
            int k  = k0 + kk;
            As[kk][rr] = (k < K) ? A[(size_t)(m0 + rr) * K + k] : 0.f;
            Bs[kk][rr] = (k < K) ? Bm[(size_t)(n0 + rr) * K + k] : 0.f;
        }
        __syncthreads();
        #pragma unroll
        for (int kk = 0; kk < 16; kk++) {
            float a[4], b[4];
            #pragma unroll
            for (int i = 0; i < 4; i++) { a[i] = As[kk][ty * 4 + i]; b[i] = Bs[kk][tx * 4 + i]; }
            #pragma unroll
            for (int i = 0; i < 4; i++)
                #pragma unroll
                for (int j = 0; j < 4; j++)
                    acc[i][j] += a[i] * b[j];
        }
        __syncthreads();
    }
    #pragma unroll
    for (int i = 0; i < 4; i++) {
        int m = m0 + ty * 4 + i;
        #pragma unroll
        for (int j = 0; j < 4; j++) {
            int n = n0 + tx * 4 + j;
            C[(size_t)m * GDIM + n] = acc[i][j] + bias1[n] + bias2[n];
        }
    }
}

// ---------------------------------------------------------------------------
// Fast device math
// ---------------------------------------------------------------------------
__device__ __forceinline__ float fsig(float x) {
    return __builtin_amdgcn_rcpf(1.f + __builtin_amdgcn_exp2f(-L2E * x));
}
__device__ __forceinline__ float ftanh(float x) {
    return 2.f * __builtin_amdgcn_rcpf(1.f + __builtin_amdgcn_exp2f(-2.f * L2E * x)) - 1.f;
}
__device__ __forceinline__ unsigned ald(const unsigned* p) {
    return __hip_atomic_load(p, __ATOMIC_RELAXED, __HIP_MEMORY_SCOPE_AGENT);
}
__device__ __forceinline__ void ast(float* p, float v) {
    __hip_atomic_store((unsigned*)p, __float_as_uint(v),
                       __ATOMIC_RELAXED, __HIP_MEMORY_SCOPE_AGENT);
}
__device__ __forceinline__ float4 poll4(const unsigned* p) {
    unsigned a = SENT, b = SENT, c = SENT, d = SENT;
    int gd = 0;
    do {
        if (a == SENT) a = ald(p + 0);
        if (b == SENT) b = ald(p + 1);
        if (c == SENT) c = ald(p + 2);
        if (d == SENT) d = ald(p + 3);
    } while (((a == SENT) | (b == SENT) | (c == SENT) | (d == SENT)) && ++gd < (1 << 20));
    return make_float4(__uint_as_float(a), __uint_as_float(b),
                       __uint_as_float(c), __uint_as_float(d));
}

// ---------------------------------------------------------------------------
// Kernel 3: fused 2-layer LSTM. 12 WGs x 640 threads (10 waves).
//   Blocks 0..3  = layer 1: WG owns 64 h-elems, 256 gate rows, Whh0 slice in
//                  registers (128 f/thread); x-gates precomputed in G1.
//   Blocks 4..11 = layer 2: WG owns 32 h-elems, 128 gate rows, Whh1 AND Wih1
//                  slices in registers (64+64 f/thread).
// Roles: wave0 = dedicated h poller (write-once sentinel rows, 1 LLC RT) ->
// LDS hbuf + hflag release (no sleep). wave1 (L2 only) = x poller (ys1[t]),
// double-buffered xbuf, back-gated by hflag (lap-safe). Waves 2..9 compute:
// lane = rowgrp(2b)<<4 | chunk(4b); each lane covers 16 dims x (8 rows L1 /
// 4+4 rows L2) from registers; butterfly reduce over 16 chunk lanes gives
// every lane the full sums -> uniform nonlinearity; chunk0 lanes store h.
// hbuf is single-buffered: wave0 can only overwrite after the FULL row t is
// published, which requires this WG's own compute waves to have stored ->
// they are done reading. XOR-swizzled LDS (idx p^(p>>2)) -> <=2-way banks.
// waves_per_eu(2): 10 waves needs <=3 waves/SIMD; min 2 -> 256-VGPR budget
// so the 128-float weight arrays stay register-resident.
// ---------------------------------------------------------------------------
__global__ __attribute__((amdgpu_flat_work_group_size(640, 640),
                          amdgpu_waves_per_eu(2)))
void lstm_fused(
    const float* __restrict__ G1,
    const float* __restrict__ Whh0,
    const float* __restrict__ Wih1,
    const float* __restrict__ Whh1,
    const float* __restrict__ b_ih1,
    const float* __restrict__ b_hh1,
    const float* __restrict__ h0,
    const float* __restrict__ c0,
    float* ys1, float* ys2, float* out)
{
    const int  blk   = blockIdx.x;
    const bool isL2  = blk >= 4;
    const int  layer = isL2 ? 1 : 0;
    const int  tid   = threadIdx.x;
    const int  wv    = tid >> 6;
    const int  lane  = tid & 63;
    const int  rg    = lane >> 4;      // rowgroup 0..3
    const int  c     = lane & 15;      // k-chunk 0..15 (16 dims each)

    __shared__ __align__(16) float4 hbuf4[64];
    __shared__ __align__(16) float4 xbuf4[2][64];
    __shared__ int hflag;
    __shared__ int xflag;

    if (tid == 0) { hflag = 0; xflag = 0; }
    __syncthreads();

    float* ysL = isL2 ? ys2 : ys1;

    // ---------------- wave 0: h poller ----------------
    if (wv == 0) {
        for (int t = 0; t < NB; t++) {
            float4 hv;
            if (t == 0) hv = ((const float4*)(h0 + layer * HDIM))[lane];
            else        hv = poll4((const unsigned*)&ysL[(size_t)(t - 1) * HDIM + 4 * lane]);
            hbuf4[lane ^ (lane >> 2)] = hv;
            __hip_atomic_store(&hflag, t + 1, __ATOMIC_RELEASE,
                               __HIP_MEMORY_SCOPE_WORKGROUP);
        }
        return;
    }

    // ---------------- wave 1: x poller (L2 only) ----------------
    if (wv == 1) {
        if (isL2) {
            for (int u = 0; u < NB; u++) {
                float4 xv = poll4((const unsigned*)&ys1[(size_t)u * HDIM + 4 * lane]);
                if (u >= 2) {   // lap-safety: compute waves must be past step u-2
                    int gd = 0;
                    while (__hip_atomic_load(&hflag, __ATOMIC_ACQUIRE,
                                             __HIP_MEMORY_SCOPE_WORKGROUP) < u) {
                        if (++gd > (1 << 20)) break;
                    }
                }
                xbuf4[u & 1][lane ^ (lane >> 2)] = xv;
                __hip_atomic_store(&xflag, u + 1, __ATOMIC_RELEASE,
                                   __HIP_MEMORY_SCOPE_WORKGROUP);
            }
        }
        return;
    }

    // ---------------- compute waves (wv 2..9) ----------------
    const int v2 = wv - 2;    // 0..7

    if (!isL2) {
        // -------- layer 1 --------
        const int e0  = blk * 64 + v2 * 8;
        const int ep0 = e0 + 2 * rg;          // this lane-group's 2 elems
        float4 wr[32];                        // [r=g*2+j][d] : Whh0 rows
        #pragma unroll
        for (int g = 0; g < 4; g++)
            #pragma unroll
            for (int j = 0; j < 2; j++)
                #pragma unroll
                for (int d = 0; d < 4; d++)
                    wr[(g * 2 + j) * 4 + d] =
                        *(const float4*)(Whh0 + (size_t)(g * 256 + ep0 + j) * HDIM
                                         + c * 16 + d * 4);
        float cA = c0[ep0], cB = c0[ep0 + 1];

        for (int t = 0; t < NB; t++) {
            float greg[8];
            #pragma unroll
            for (int r = 0; r < 8; r++)
                greg[r] = G1[(size_t)t * GDIM + (r >> 1) * 256 + ep0 + (r & 1)];

            {   int gd = 0;
                while (__hip_atomic_load(&hflag, __ATOMIC_ACQUIRE,
                                         __HIP_MEMORY_SCOPE_WORKGROUP) < t + 1) {
                    if (++gd > (1 << 20)) break;
                }
            }

            float4 h4[4];
            #pragma unroll
            for (int d = 0; d < 4; d++) h4[d] = hbuf4[(4 * c + d) ^ c];

            float acc[8] = {0.f, 0.f, 0.f, 0.f, 0.f, 0.f, 0.f, 0.f};
            #pragma unroll
            for (int d = 0; d < 4; d++) {
                float4 hv = h4[d];
                #pragma unroll
                for (int r = 0; r < 8; r++) {
                    float4 w4 = wr[r * 4 + d];
                    acc[r] += hv.x * w4.x + hv.y * w4.y + hv.z * w4.z + hv.w * w4.w;
                }
            }
            #pragma unroll
            for (int m = 1; m < 16; m <<= 1)
                #pragma unroll
                for (int r = 0; r < 8; r++) acc[r] += __shfl_xor(acc[r], m);

            float gs[8];
            #pragma unroll
            for (int r = 0; r < 8; r++) gs[r] = acc[r] + greg[r];

            float iA = fsig(gs[0]), iB = fsig(gs[1]);
            float fA = fsig(gs[2]), fB = fsig(gs[3]);
            float gA = ftanh(gs[4]), gB = ftanh(gs[5]);
            float oA = fsig(gs[6]), oB = fsig(gs[7]);
            cA = fA * cA + iA * gA;
            cB = fB * cB + iB * gB;
            float hA = oA * ftanh(cA);
            float hB = oB * ftanh(cB);

            if (c == 0) {
                ast(&ys1[(size_t)t * HDIM + ep0],     hA);
                ast(&ys1[(size_t)t * HDIM + ep0 + 1], hB);
                if (t == NB - 1) {
                    out[1024 + ep0] = hA; out[1024 + ep0 + 1] = hB;   // hn L0
                    out[1536 + ep0] = cA; out[1536 + ep0 + 1] = cB;   // cn L0
                }
            }
        }
    } else {
        // -------- layer 2 --------
        const int e0 = (blk - 4) * 32 + v2 * 4;
        const int ep = e0 + rg;               // this lane-group's elem
        float4 wr[32];                        // 0..15: Whh1[g][d], 16..31: Wih1[g][d]
        float bs[4];
        #pragma unroll
        for (int g = 0; g < 4; g++) {
            #pragma unroll
            for (int d = 0; d < 4; d++) {
                wr[g * 4 + d] =
                    *(const float4*)(Whh1 + (size_t)(g * 256 + ep) * HDIM + c * 16 + d * 4);
                wr[16 + g * 4 + d] =
                    *(const float4*)(Wih1 + (size_t)(g * 256 + ep) * HDIM + c * 16 + d * 4);
            }
            bs[g] = b_ih1[g * 256 + ep] + b_hh1[g * 256 + ep];
        }
        float cE = c0[HDIM + ep];

        for (int t = 0; t < NB; t++) {
            {   int gd = 0;
                while (__hip_atomic_load(&hflag, __ATOMIC_ACQUIRE,
                                         __HIP_MEMORY_SCOPE_WORKGROUP) < t + 1) {
                    if (++gd > (1 << 20)) break;
                }
                gd = 0;
                while (__hip_atomic_load(&xflag, __ATOMIC_ACQUIRE,
                                         __HIP_MEMORY_SCOPE_WORKGROUP) < t + 1) {
                    if (++gd > (1 << 20)) break;
                }
            }

            float4 h4[4], x4[4];
            #pragma unroll
            for (int d = 0; d < 4; d++) {
                h4[d] = hbuf4[(4 * c + d) ^ c];
                x4[d] = xbuf4[t & 1][(4 * c + d) ^ c];
            }

            float acc[4] = {0.f, 0.f, 0.f, 0.f};
            #pragma unroll
            for (int d = 0; d < 4; d++) {
                float4 hv = h4[d];
                #pragma unroll
                for (int g = 0; g < 4; g++) {
                    float4 w4 = wr[g * 4 + d];
                    acc[g] += hv.x * w4.x + hv.y * w4.y + hv.z * w4.z + hv.w * w4.w;
                }
            }
            #pragma unroll
            for (int d = 0; d < 4; d++) {
                float4 xv = x4[d];
                #pragma unroll
                for (int g = 0; g < 4; g++) {
                    float4 w4 = wr[16 + g * 4 + d];
                    acc[g] += xv.x * w4.x + xv.y * w4.y + xv.z * w4.z + xv.w * w4.w;
                }
            }
            #pragma unroll
            for (int m = 1; m < 16; m <<= 1)
                #pragma unroll
                for (int g = 0; g < 4; g++) acc[g] += __shfl_xor(acc[g], m);

            float gi = acc[0] + bs[0], gf = acc[1] + bs[1];
            float gg = acc[2] + bs[2], go = acc[3] + bs[3];
            float iv = fsig(gi), fv = fsig(gf), gv = ftanh(gg), ov = fsig(go);
            cE = fv * cE + iv * gv;
            float hE = ov * ftanh(cE);

            if (c == 0) {
                ast(&ys2[(size_t)t * HDIM + ep], hE);
                if (t == NB - 1) {
                    out[1024 + HDIM + ep] = hE;   // hn L1
                    out[1536 + HDIM + ep] = cE;   // cn L1
                }
            }
        }
    }
}

// ---------------------------------------------------------------------------
// Kernel 4: fc head
// ---------------------------------------------------------------------------
__global__ __launch_bounds__(256) void fc_kernel(const float* __restrict__ ys2,
                                                 const float* __restrict__ fc_w,
                                                 const float* __restrict__ fc_b,
                                                 float* __restrict__ out) {
    const int row  = blockIdx.x * 4 + (threadIdx.x >> 6);
    const int lane = threadIdx.x & 63;
    float4 y = ((const float4*)(ys2 + (size_t)row * HDIM))[lane];
    float4 wv = ((const float4*)fc_w)[lane];
    float d = y.x * wv.x + y.y * wv.y + y.z * wv.z + y.w * wv.w;
    #pragma unroll
    for (int m = 1; m < 64; m <<= 1) d += __shfl_xor(d, m);
    if (lane == 0) out[row] = 1.f / (1.f + expf(-(d + fc_b[0])));
}

// ---------------------------------------------------------------------------
extern "C" void kernel_launch(void* const* d_in, const int* in_sizes, int n_in,
                              void* d_out, int out_size, void* d_ws, size_t ws_size,
                              hipStream_t stream) {
    const int*   x     = (const int*)  d_in[0];
    const float* h0    = (const float*)d_in[1];
    const float* c0    = (const float*)d_in[2];
    const float* emb   = (const float*)d_in[3];
    const float* w_ih0 = (const float*)d_in[4];
    const float* w_hh0 = (const float*)d_in[5];
    const float* b_ih0 = (const float*)d_in[6];
    const float* b_hh0 = (const float*)d_in[7];
    const float* w_ih1 = (const float*)d_in[8];
    const float* w_hh1 = (const float*)d_in[9];
    const float* b_ih1 = (const float*)d_in[10];
    const float* b_hh1 = (const float*)d_in[11];
    const float* fc_w  = (const float*)d_in[12];
    const float* fc_b  = (const float*)d_in[13];
    float* out = (float*)d_out;

    // workspace layout (floats)
    float* X   = (float*)d_ws;                  // 1024*903
    float* G1  = X + (size_t)NB * DIN;          // 1024*1024
    float* ys1 = G1 + (size_t)NB * GDIM;        // 1024*256
    float* ys2 = ys1 + (size_t)NB * HDIM;       // 1024*256

    // sentinel-fill both exchange buffers (0xFFFFFFFF = NaN, never produced)
    hipMemsetAsync(ys1, 0xFF, 2 * (size_t)NB * HDIM * sizeof(float), stream);

    conv_kernel<<<NB, 256, 0, stream>>>(x, emb, X);

    gemm_bias<<<dim3(16, 16), 256, 0, stream>>>(X, w_ih0, b_ih0, b_hh0, G1, DIN);

    lstm_fused<<<12, 640, 0, stream>>>(G1, w_hh0, w_ih1, w_hh1, b_ih1, b_hh1,
                                       h0, c0, ys1, ys2, out);

    fc_kernel<<<NB / 4, 256, 0, stream>>>(ys2, fc_w, fc_b, out);
}